// Round 7
// baseline (89.809 us; speedup 1.0000x reference)
//
#include <hip/hip_runtime.h>

// LogicConv3d: B=4, C=3, H=W=D=32, K=32, S=16 leaves, tree depth 4 (31 LUT nodes).
// Out: (B, K, 30, 30, 30) = 3,456,000 fp32.
//
// R6: 8 consecutive od per thread (od0 = {0,8,16,22}; g=3 overlaps g=2 by 2 ->
// duplicate identical stores; leaf reads stay inside the 32-dword d-row).
// Halves per-output overhead (address adds, wave-uniform const ds_reads, store
// setup) vs R5's 4-od quads; VALU eval floor unchanged (~12 us chip-wide).
// Levels 0+1 fused per leaf-pair to cap live state at ~64 VGPR of accumulators
// (R3 lesson: hoisting 128+ floats spilled to scratch -> 2 GB HBM traffic).
// Block covers 2 oh rows; leaf bases in SGPRs; gather = v_add + global_load.

#define B_  4
#define C_  3
#define H_  32
#define W_  32
#define D_  32
#define K_  32
#define S_  16
#define TPB 256

typedef float v8f __attribute__((ext_vector_type(8), aligned(4)));

__device__ __forceinline__ v8f lut8(v8f a, v8f b, float l0, float d1, float d2, float d3) {
    // E = l0 + a*d2 + b*d1 + (a*b)*d3  -> 16 pk-instrs for 8 positions
    v8f t = a * d2 + l0;
    t = b * d1 + t;
    t = (a * b) * d3 + t;
    return t;
}

__global__ __launch_bounds__(TPB, 3) void logic_conv3d(
    const float* __restrict__ x,
    const int*   __restrict__ kc,
    const float* __restrict__ w0,
    const float* __restrict__ w1,
    const float* __restrict__ w2,
    const float* __restrict__ w3,
    const float* __restrict__ w4,
    float*       __restrict__ out)
{
    __shared__ float4 s_lut[31];     // (l0, d1, d2, d3) per node
    __shared__ int    s_lb[32];      // leaf dword base in flattened (C,H,W,D), oh-independent

    const int bk  = blockIdx.x;      // b*K + k
    const int b   = bk >> 5;
    const int k   = bk & 31;
    const int tid = threadIdx.x;

    // ---- per-block setup: 31 softmax->LUT (delta form) + 32 leaf bases ----
    if (tid < 31) {
        const float* wp; int ln;
        if      (tid < 16) { wp = w0; ln = tid;      }
        else if (tid < 24) { wp = w1; ln = tid - 16; }
        else if (tid < 28) { wp = w2; ln = tid - 24; }
        else if (tid < 30) { wp = w3; ln = tid - 28; }
        else               { wp = w4; ln = 0;        }
        const float* wrow = wp + (ln * K_ + k) * 16;
        float lg[16];
        float m = -1e30f;
        #pragma unroll
        for (int g = 0; g < 16; ++g) { lg[g] = wrow[g]; m = fmaxf(m, lg[g]); }
        float z = 0.f;
        #pragma unroll
        for (int g = 0; g < 16; ++g) { lg[g] = __expf(lg[g] - m); z += lg[g]; }
        const float inv = 1.0f / z;
        float l0 = 0.f, l1 = 0.f, l2 = 0.f, l3 = 0.f;
        #pragma unroll
        for (int g = 0; g < 16; ++g) {
            float p = lg[g] * inv;           // GATES[g,t] = (g>>t)&1, t = 2*a+b
            if (g & 1) l0 += p;
            if (g & 2) l1 += p;
            if (g & 4) l2 += p;
            if (g & 8) l3 += p;
        }
        s_lut[tid] = make_float4(l0, l1 - l0, l2 - l0, (l3 - l2) - (l1 - l0));
    } else if (tid >= 32 && tid < 64) {
        const int idx  = tid - 32;           // tree*16 + s
        const int tree = idx >> 4;
        const int s    = idx & 15;
        const int off  = ((tree * K_ + k) * S_ + s) * 4;  // kc (2,K,S,4) = (h,w,d,c)
        const int h = kc[off + 0], w = kc[off + 1], d = kc[off + 2], c = kc[off + 3];
        s_lb[idx] = ((c * H_ + h) * W_ + w) * D_ + d;
    }
    __syncthreads();

    // block-uniform leaf bases -> SGPRs
    int sA[16], sB[16];
    #pragma unroll
    for (int s = 0; s < 16; ++s) {
        sA[s] = __builtin_amdgcn_readfirstlane(s_lb[s]);
        sB[s] = __builtin_amdgcn_readfirstlane(s_lb[16 + s]);
    }

    // thread -> (oh_local, ow, octet of consecutive od)
    const int g   = tid & 3;
    const int woi = tid >> 2;                // 0..63
    const int ohl = woi >> 5;                // 0 or 1 (two oh rows per block)
    int ow        = woi & 31;
    if (ow > 29) ow = 29;                    // duplicate work, no OOB / divergence
    const int od0 = (g < 3) ? (g << 3) : 22; // 0,8,16,22; g=3 overlaps g=2 by 2
    const int oh  = blockIdx.y * 2 + ohl;
    const int vo  = ohl * (W_ * D_) + ow * D_ + od0;   // per-thread dword offset

    // fold batch + block's first oh row into scalar base
    const float* xb2 = x + (size_t)b * (C_ * H_ * W_ * D_) + (blockIdx.y * 2) * (W_ * D_);

    // ---- fused levels 0+1: leaf pair -> level-1 node (caps live state) ----
    v8f v1[8];
    #pragma unroll
    for (int j = 0; j < 8; ++j) {
        const int s0 = 2 * j, s1 = 2 * j + 1;
        const v8f A0 = *(const v8f*)(xb2 + sA[s0] + vo);
        const v8f B0 = *(const v8f*)(xb2 + sB[s0] + vo);
        const float4 L0 = s_lut[s0];
        const v8f t0 = lut8(A0, B0, L0.x, L0.y, L0.z, L0.w);
        const v8f A1 = *(const v8f*)(xb2 + sA[s1] + vo);
        const v8f B1 = *(const v8f*)(xb2 + sB[s1] + vo);
        const float4 L1 = s_lut[s1];
        const v8f t1 = lut8(A1, B1, L1.x, L1.y, L1.z, L1.w);
        const float4 LN = s_lut[16 + j];
        v1[j] = lut8(t0, t1, LN.x, LN.y, LN.z, LN.w);
    }

    // ---- levels 2..4: widths 4,2,1 at node offsets 24,28,30 ----
    #pragma unroll
    for (int j = 0; j < 4; ++j) {
        const float4 L = s_lut[24 + j];
        v1[j] = lut8(v1[2 * j], v1[2 * j + 1], L.x, L.y, L.z, L.w);
    }
    #pragma unroll
    for (int j = 0; j < 2; ++j) {
        const float4 L = s_lut[28 + j];
        v1[j] = lut8(v1[2 * j], v1[2 * j + 1], L.x, L.y, L.z, L.w);
    }
    {
        const float4 L = s_lut[30];
        v1[0] = lut8(v1[0], v1[1], L.x, L.y, L.z, L.w);
    }

    // store 8 consecutive od (overlap/duplicate threads write identical values)
    float* outp = out + (size_t)bk * 27000 + oh * 900 + ow * 30 + od0;
    *(v8f*)outp = v1[0];
}

extern "C" void kernel_launch(void* const* d_in, const int* in_sizes, int n_in,
                              void* d_out, int out_size, void* d_ws, size_t ws_size,
                              hipStream_t stream) {
    const float* x  = (const float*)d_in[0];
    const int*   kc = (const int*)d_in[1];
    const float* w0 = (const float*)d_in[2];
    const float* w1 = (const float*)d_in[3];
    const float* w2 = (const float*)d_in[4];
    const float* w3 = (const float*)d_in[5];
    const float* w4 = (const float*)d_in[6];
    float* out = (float*)d_out;

    dim3 grid(B_ * K_, 15);  // (bk, oh-pair) = 1920 blocks
    logic_conv3d<<<grid, TPB, 0, stream>>>(x, kc, w0, w1, w2, w3, w4, out);
}

// Round 8
// 89.613 us; speedup vs baseline: 1.0022x; 1.0022x over previous
//
#include <hip/hip_runtime.h>

// LogicConv3d: B=4, C=3, H=W=D=32, K=32, S=16 leaves, tree depth 4 (31 LUT nodes).
// Out: (B, K, 30, 30, 30) = 3,456,000 fp32.
//
// R7: R5's eval structure (4-od quads, per-leaf consumption — proven no-spill)
// with gathers moved to an LDS slab: 3c x 3h x 32w x 33d-padded = 38 KB,
// staged with coalesced float4 loads. Leaf gather = one ds_read_b128 at
// deterministic ~25cyc latency (R5/R6 evidence: global-gather latency, not
// instruction issue, is the bottleneck — halving overhead did nothing).
// WS=33 (%32==1) rotates banks across ow -> staging writes <=2-way (free),
// gather reads spread near-uniformly. Fixes R3's 3 mistakes: no SoA hoisting
// (spill), no WS=36 (4-bank pile-up), 38 KB not 41.5 KB (4 blocks/CU).

#define B_  4
#define C_  3
#define H_  32
#define W_  32
#define D_  32
#define K_  32
#define S_  16
#define WS  33      // padded d-row stride (dwords)
#define TPB 256

typedef float v4f __attribute__((ext_vector_type(4), aligned(4)));

__device__ __forceinline__ v4f lut4(v4f a, v4f b, float l0, float d1, float d2, float d3) {
    // E = l0 + a*d2 + b*d1 + (a*b)*d3  -> 8 pk-instrs for 4 positions
    v4f t = a * d2 + l0;
    t = b * d1 + t;
    t = (a * b) * d3 + t;
    return t;
}

__global__ __launch_bounds__(TPB, 4) void logic_conv3d(
    const float* __restrict__ x,
    const int*   __restrict__ kc,
    const float* __restrict__ w0,
    const float* __restrict__ w1,
    const float* __restrict__ w2,
    const float* __restrict__ w3,
    const float* __restrict__ w4,
    float*       __restrict__ out)
{
    __shared__ float4 s_lut[31];                 // (l0, d1, d2, d3) per node
    __shared__ int    s_lb[32];                  // leaf base in slab coords
    __shared__ __align__(16) float slab[9 * 32 * WS];  // 9504 dwords = 38016 B

    const int bk  = blockIdx.x;      // b*K + k
    const int oh  = blockIdx.y;      // 0..29
    const int b   = bk >> 5;
    const int k   = bk & 31;
    const int tid = threadIdx.x;

    // ---- per-block setup: 31 softmax->LUT (delta form) + 32 slab-coord bases ----
    if (tid < 31) {
        const float* wp; int ln;
        if      (tid < 16) { wp = w0; ln = tid;      }
        else if (tid < 24) { wp = w1; ln = tid - 16; }
        else if (tid < 28) { wp = w2; ln = tid - 24; }
        else if (tid < 30) { wp = w3; ln = tid - 28; }
        else               { wp = w4; ln = 0;        }
        const float* wrow = wp + (ln * K_ + k) * 16;
        float lg[16];
        float m = -1e30f;
        #pragma unroll
        for (int g = 0; g < 16; ++g) { lg[g] = wrow[g]; m = fmaxf(m, lg[g]); }
        float z = 0.f;
        #pragma unroll
        for (int g = 0; g < 16; ++g) { lg[g] = __expf(lg[g] - m); z += lg[g]; }
        const float inv = 1.0f / z;
        float l0 = 0.f, l1 = 0.f, l2 = 0.f, l3 = 0.f;
        #pragma unroll
        for (int g = 0; g < 16; ++g) {
            float p = lg[g] * inv;           // GATES[g,t] = (g>>t)&1, t = 2*a+b
            if (g & 1) l0 += p;
            if (g & 2) l1 += p;
            if (g & 4) l2 += p;
            if (g & 8) l3 += p;
        }
        s_lut[tid] = make_float4(l0, l1 - l0, l2 - l0, (l3 - l2) - (l1 - l0));
    } else if (tid >= 32 && tid < 64) {
        const int idx  = tid - 32;           // tree*16 + s
        const int tree = idx >> 4;
        const int s    = idx & 15;
        const int off  = ((tree * K_ + k) * S_ + s) * 4;  // kc (2,K,S,4) = (h,w,d,c)
        const int h = kc[off + 0], w = kc[off + 1], d = kc[off + 2], c = kc[off + 3];
        s_lb[idx] = ((c * 3 + h) * 32 + w) * WS + d;      // slab coords
    }

    // ---- stage slab: 9 planes of 32x32 dwords, coalesced float4 reads ----
    {
        const float* xb = x + (size_t)b * (C_ * H_ * W_ * D_);
        const int w  = tid >> 3;             // 0..31
        const int d4 = (tid & 7) << 2;       // 0,4,...,28
        #pragma unroll
        for (int it = 0; it < 9; ++it) {
            const int c  = it / 3;
            const int dh = it - 3 * c;
            const float4 val = *(const float4*)(xb + c * (H_ * W_ * D_) + (oh + dh) * (W_ * D_) + tid * 4);
            *(float4*)&slab[(it * 32 + w) * WS + d4] = val;  // (w + d4) % 32 aliases <=2-way: free
        }
    }
    __syncthreads();

    // block-uniform leaf bases -> SGPRs
    int sA[16], sB[16];
    #pragma unroll
    for (int s = 0; s < 16; ++s) {
        sA[s] = __builtin_amdgcn_readfirstlane(s_lb[s]);
        sB[s] = __builtin_amdgcn_readfirstlane(s_lb[16 + s]);
    }

    // thread -> (ow, quad of consecutive od)
    const int g   = tid & 7;
    int ow        = tid >> 3;
    if (ow > 29) ow = 29;                    // duplicate work, no OOB / divergence
    const int od0 = (g < 7) ? (g << 2) : 26; // 0,4,...,24,26; g=7 overlaps g=6 by 2
    const int vo  = ow * WS + od0;           // per-thread dword offset within slab

    v4f v[16];
    #pragma unroll
    for (int s = 0; s < 16; ++s) {
        const v4f A  = *(const v4f*)&slab[sA[s] + vo];
        const v4f Bv = *(const v4f*)&slab[sB[s] + vo];
        const float4 L = s_lut[s];
        v[s] = lut4(A, Bv, L.x, L.y, L.z, L.w);
    }

    #pragma unroll
    for (int lvl = 0; lvl < 4; ++lvl) {
        const int width = 8 >> lvl;              // 8,4,2,1
        const int nbase = (lvl == 0) ? 16 : (lvl == 1) ? 24 : (lvl == 2) ? 28 : 30;
        #pragma unroll
        for (int j = 0; j < width; ++j) {
            const float4 L = s_lut[nbase + j];
            v[j] = lut4(v[2 * j], v[2 * j + 1], L.x, L.y, L.z, L.w);
        }
    }

    // store 4 consecutive od (overlap/duplicate threads write identical values)
    float* outp = out + (size_t)bk * 27000 + oh * 900 + ow * 30 + od0;
    *(v4f*)outp = v[0];
}

extern "C" void kernel_launch(void* const* d_in, const int* in_sizes, int n_in,
                              void* d_out, int out_size, void* d_ws, size_t ws_size,
                              hipStream_t stream) {
    const float* x  = (const float*)d_in[0];
    const int*   kc = (const int*)d_in[1];
    const float* w0 = (const float*)d_in[2];
    const float* w1 = (const float*)d_in[3];
    const float* w2 = (const float*)d_in[4];
    const float* w3 = (const float*)d_in[5];
    const float* w4 = (const float*)d_in[6];
    float* out = (float*)d_out;

    dim3 grid(B_ * K_, 30);  // (bk, oh) = 3840 blocks
    logic_conv3d<<<grid, TPB, 0, stream>>>(x, kc, w0, w1, w2, w3, w4, out);
}

// Round 9
// 89.610 us; speedup vs baseline: 1.0022x; 1.0000x over previous
//
#include <hip/hip_runtime.h>

// LogicConv3d: B=4, C=3, H=W=D=32, K=32, S=16 leaves, tree depth 4 (31 LUT nodes).
// Out: (B, K, 30, 30, 30) = 3,456,000 fp32.
//
// R8 = R7 (LDS slab, 4-od quads, per-leaf consumption) +
//  (a) 3-FMA node eval: E = fma(b, fma(a,d3,d1), fma(a,d2,l0))  (was 4 ops)
//  (b) no ow duplication: tid>=240 stage but idle during eval/store
// Cycle model: eval VALU ~12.4us -> ~9.3us chip-wide; LDS gather pipe ~10us;
// measured R7 ~29.6us = poor overlap of these. Work reduction, not layout.

#define B_  4
#define C_  3
#define H_  32
#define W_  32
#define D_  32
#define K_  32
#define S_  16
#define WS  33      // padded d-row stride (dwords); %32==1 rotates banks per ow
#define TPB 256

typedef float v4f __attribute__((ext_vector_type(4), aligned(4)));

__device__ __forceinline__ v4f lut4(v4f a, v4f b, float l0, float d1, float d2, float d3) {
    // E = l0 + a*d2 + b*d1 + (a*b)*d3  ==  fma(b, fma(a,d3,d1), fma(a,d2,l0))
    const v4f t0 = a * d2 + l0;
    const v4f t1 = a * d3 + d1;
    return b * t1 + t0;              // 3 fma -> 6 pk-instrs per 4 positions
}

__global__ __launch_bounds__(TPB, 4) void logic_conv3d(
    const float* __restrict__ x,
    const int*   __restrict__ kc,
    const float* __restrict__ w0,
    const float* __restrict__ w1,
    const float* __restrict__ w2,
    const float* __restrict__ w3,
    const float* __restrict__ w4,
    float*       __restrict__ out)
{
    __shared__ float4 s_lut[31];                 // (l0, d1, d2, d3) per node
    __shared__ int    s_lb[32];                  // leaf base in slab coords
    __shared__ __align__(16) float slab[9 * 32 * WS];  // 9504 dwords = 38016 B

    const int bk  = blockIdx.x;      // b*K + k
    const int oh  = blockIdx.y;      // 0..29
    const int b   = bk >> 5;
    const int k   = bk & 31;
    const int tid = threadIdx.x;

    // ---- per-block setup: 31 softmax->LUT (delta form) + 32 slab-coord bases ----
    if (tid < 31) {
        const float* wp; int ln;
        if      (tid < 16) { wp = w0; ln = tid;      }
        else if (tid < 24) { wp = w1; ln = tid - 16; }
        else if (tid < 28) { wp = w2; ln = tid - 24; }
        else if (tid < 30) { wp = w3; ln = tid - 28; }
        else               { wp = w4; ln = 0;        }
        const float* wrow = wp + (ln * K_ + k) * 16;
        float lg[16];
        float m = -1e30f;
        #pragma unroll
        for (int g = 0; g < 16; ++g) { lg[g] = wrow[g]; m = fmaxf(m, lg[g]); }
        float z = 0.f;
        #pragma unroll
        for (int g = 0; g < 16; ++g) { lg[g] = __expf(lg[g] - m); z += lg[g]; }
        const float inv = 1.0f / z;
        float l0 = 0.f, l1 = 0.f, l2 = 0.f, l3 = 0.f;
        #pragma unroll
        for (int g = 0; g < 16; ++g) {
            float p = lg[g] * inv;           // GATES[g,t] = (g>>t)&1, t = 2*a+b
            if (g & 1) l0 += p;
            if (g & 2) l1 += p;
            if (g & 4) l2 += p;
            if (g & 8) l3 += p;
        }
        s_lut[tid] = make_float4(l0, l1 - l0, l2 - l0, (l3 - l2) - (l1 - l0));
    } else if (tid >= 32 && tid < 64) {
        const int idx  = tid - 32;           // tree*16 + s
        const int tree = idx >> 4;
        const int s    = idx & 15;
        const int off  = ((tree * K_ + k) * S_ + s) * 4;  // kc (2,K,S,4) = (h,w,d,c)
        const int h = kc[off + 0], w = kc[off + 1], d = kc[off + 2], c = kc[off + 3];
        s_lb[idx] = ((c * 3 + h) * 32 + w) * WS + d;      // slab coords
    }

    // ---- stage slab: 9 planes of 32x32 dwords, coalesced float4 reads ----
    {
        const float* xb = x + (size_t)b * (C_ * H_ * W_ * D_);
        const int w  = tid >> 3;             // 0..31
        const int d4 = (tid & 7) << 2;       // 0,4,...,28
        #pragma unroll
        for (int it = 0; it < 9; ++it) {
            const int c  = it / 3;
            const int dh = it - 3 * c;
            const float4 val = *(const float4*)(xb + c * (H_ * W_ * D_) + (oh + dh) * (W_ * D_) + tid * 4);
            *(float4*)&slab[(it * 32 + w) * WS + d4] = val;
        }
    }
    __syncthreads();

    // threads 240..255: staging done, no eval (ow would duplicate 29)
    if (tid < 240) {
        // block-uniform leaf bases -> SGPRs
        int sA[16], sB[16];
        #pragma unroll
        for (int s = 0; s < 16; ++s) {
            sA[s] = __builtin_amdgcn_readfirstlane(s_lb[s]);
            sB[s] = __builtin_amdgcn_readfirstlane(s_lb[16 + s]);
        }

        const int g   = tid & 7;
        const int ow  = tid >> 3;                // 0..29 exact
        const int od0 = (g < 7) ? (g << 2) : 26; // 0,4,...,24,26; g=7 overlaps g=6 by 2
        const int vo  = ow * WS + od0;

        v4f v[16];
        #pragma unroll
        for (int s = 0; s < 16; ++s) {
            const v4f A  = *(const v4f*)&slab[sA[s] + vo];
            const v4f Bv = *(const v4f*)&slab[sB[s] + vo];
            const float4 L = s_lut[s];
            v[s] = lut4(A, Bv, L.x, L.y, L.z, L.w);
        }

        #pragma unroll
        for (int lvl = 0; lvl < 4; ++lvl) {
            const int width = 8 >> lvl;              // 8,4,2,1
            const int nbase = (lvl == 0) ? 16 : (lvl == 1) ? 24 : (lvl == 2) ? 28 : 30;
            #pragma unroll
            for (int j = 0; j < width; ++j) {
                const float4 L = s_lut[nbase + j];
                v[j] = lut4(v[2 * j], v[2 * j + 1], L.x, L.y, L.z, L.w);
            }
        }

        float* outp = out + (size_t)bk * 27000 + oh * 900 + ow * 30 + od0;
        *(v4f*)outp = v[0];
    }
}

extern "C" void kernel_launch(void* const* d_in, const int* in_sizes, int n_in,
                              void* d_out, int out_size, void* d_ws, size_t ws_size,
                              hipStream_t stream) {
    const float* x  = (const float*)d_in[0];
    const int*   kc = (const int*)d_in[1];
    const float* w0 = (const float*)d_in[2];
    const float* w1 = (const float*)d_in[3];
    const float* w2 = (const float*)d_in[4];
    const float* w3 = (const float*)d_in[5];
    const float* w4 = (const float*)d_in[6];
    float* out = (float*)d_out;

    dim3 grid(B_ * K_, 30);  // (bk, oh) = 3840 blocks
    logic_conv3d<<<grid, TPB, 0, stream>>>(x, kc, w0, w1, w2, w3, w4, out);
}

// Round 10
// 87.487 us; speedup vs baseline: 1.0265x; 1.0243x over previous
//
#include <hip/hip_runtime.h>

// LogicConv3d: B=4, C=3, H=W=D=32, K=32, S=16 leaves, tree depth 4 (31 LUT nodes).
// Out: (B, K, 30, 30, 30) = 3,456,000 fp32.
//
// R9: kernel is LDS-issue-bound (R6/R7/R8 null results + instruction model:
// leaf-quad reads are UNALIGNED (WS odd, leaf d in {0,1,2}) -> ds_read2_b32
// pairs, intrinsic; the reducible terms are const/base/staging reads).
// -> 8 consecutive od per thread (od0={0,8,16,22}), block covers 2 oh rows
//    (slab 3c x 4h x 32w x 33d = 50.7 KB, 3 blocks/CU): halves per-output
//    const ds_reads, base reads, staging.
// -> levels 0+1 fused per leaf pair: accumulator live state capped at 64 VGPR
//    (R3 lesson: hoisting spilled to scratch -> 2 GB HBM traffic).
// -> bases: 8 aligned ds_read_b128 + readfirstlane -> 32 SGPRs.

#define B_  4
#define C_  3
#define H_  32
#define W_  32
#define D_  32
#define K_  32
#define S_  16
#define WS  33      // padded d-row stride (dwords); %32==1 rotates banks per ow
#define TPB 256

typedef float v8f __attribute__((ext_vector_type(8), aligned(4)));

__device__ __forceinline__ v8f lut8(v8f a, v8f b, float l0, float d1, float d2, float d3) {
    // E = l0 + a*d2 + b*d1 + (a*b)*d3 == fma(b, fma(a,d3,d1), fma(a,d2,l0))
    const v8f t0 = a * d2 + l0;
    const v8f t1 = a * d3 + d1;
    return b * t1 + t0;
}

__global__ __launch_bounds__(TPB, 3) void logic_conv3d(
    const float* __restrict__ x,
    const int*   __restrict__ kc,
    const float* __restrict__ w0,
    const float* __restrict__ w1,
    const float* __restrict__ w2,
    const float* __restrict__ w3,
    const float* __restrict__ w4,
    float*       __restrict__ out)
{
    __shared__ float4 s_lut[31];                 // (l0, d1, d2, d3) per node
    __shared__ int    s_lb[32];                  // leaf base in slab coords (16B-aligned)
    __shared__ __align__(16) float slab[12 * 32 * WS];  // 12672 dwords = 50688 B

    const int bk  = blockIdx.x;      // b*K + k
    const int b   = bk >> 5;
    const int k   = bk & 31;
    const int tid = threadIdx.x;

    // ---- per-block setup: 31 softmax->LUT (delta form) + 32 slab-coord bases ----
    if (tid < 31) {
        const float* wp; int ln;
        if      (tid < 16) { wp = w0; ln = tid;      }
        else if (tid < 24) { wp = w1; ln = tid - 16; }
        else if (tid < 28) { wp = w2; ln = tid - 24; }
        else if (tid < 30) { wp = w3; ln = tid - 28; }
        else               { wp = w4; ln = 0;        }
        const float* wrow = wp + (ln * K_ + k) * 16;
        float lg[16];
        float m = -1e30f;
        #pragma unroll
        for (int g = 0; g < 16; ++g) { lg[g] = wrow[g]; m = fmaxf(m, lg[g]); }
        float z = 0.f;
        #pragma unroll
        for (int g = 0; g < 16; ++g) { lg[g] = __expf(lg[g] - m); z += lg[g]; }
        const float inv = 1.0f / z;
        float l0 = 0.f, l1 = 0.f, l2 = 0.f, l3 = 0.f;
        #pragma unroll
        for (int g = 0; g < 16; ++g) {
            float p = lg[g] * inv;           // GATES[g,t] = (g>>t)&1, t = 2*a+b
            if (g & 1) l0 += p;
            if (g & 2) l1 += p;
            if (g & 4) l2 += p;
            if (g & 8) l3 += p;
        }
        s_lut[tid] = make_float4(l0, l1 - l0, l2 - l0, (l3 - l2) - (l1 - l0));
    } else if (tid >= 32 && tid < 64) {
        const int idx  = tid - 32;           // tree*16 + s
        const int tree = idx >> 4;
        const int s    = idx & 15;
        const int off  = ((tree * K_ + k) * S_ + s) * 4;  // kc (2,K,S,4) = (h,w,d,c)
        const int h = kc[off + 0], w = kc[off + 1], d = kc[off + 2], c = kc[off + 3];
        s_lb[idx] = ((c * 4 + h) * 32 + w) * WS + d;      // slab coords (4 h-rows)
    }

    // ---- stage slab: 12 planes (3c x 4h) of 32x32 dwords, coalesced float4 ----
    {
        const float* xb = x + (size_t)b * (C_ * H_ * W_ * D_) + (blockIdx.y * 2) * (W_ * D_);
        const int w  = tid >> 3;             // 0..31
        const int d4 = (tid & 7) << 2;       // 0,4,...,28
        #pragma unroll
        for (int it = 0; it < 12; ++it) {
            const int c  = it >> 2;          // 0..2
            const int dh = it & 3;           // 0..3
            const float4 val = *(const float4*)(xb + c * (H_ * W_ * D_) + dh * (W_ * D_) + tid * 4);
            *(float4*)&slab[((c * 4 + dh) * 32 + w) * WS + d4] = val;
        }
    }
    __syncthreads();

    // ---- bases: 8 aligned b128 reads + readfirstlane -> 32 SGPRs ----
    int sAB[32];
    #pragma unroll
    for (int i = 0; i < 8; ++i) {
        const int4 q = *(const int4*)&s_lb[i * 4];
        sAB[i * 4 + 0] = __builtin_amdgcn_readfirstlane(q.x);
        sAB[i * 4 + 1] = __builtin_amdgcn_readfirstlane(q.y);
        sAB[i * 4 + 2] = __builtin_amdgcn_readfirstlane(q.z);
        sAB[i * 4 + 3] = __builtin_amdgcn_readfirstlane(q.w);
    }

    // thread -> (oh_local, ow, octet of consecutive od)
    const int ohl = tid >> 7;                // 0,1
    const int r   = tid & 127;
    const int ow  = r >> 2;                  // 0..31 (>=30 inactive)
    const int gq  = r & 3;                   // 0..3
    const int od0 = (gq < 3) ? (gq << 3) : 22;  // 0,8,16,22; gq=3 overlaps gq=2 by 2

    if (ow < 30) {
        const int vo = ohl * (32 * WS) + ow * WS + od0;

        // ---- fused levels 0+1: leaf pair -> level-1 node ----
        v8f v1[8];
        #pragma unroll
        for (int j = 0; j < 8; ++j) {
            const int s0 = 2 * j, s1 = 2 * j + 1;
            const v8f A0 = *(const v8f*)&slab[sAB[s0] + vo];
            const v8f B0 = *(const v8f*)&slab[sAB[16 + s0] + vo];
            const float4 L0 = s_lut[s0];
            const v8f t0 = lut8(A0, B0, L0.x, L0.y, L0.z, L0.w);
            const v8f A1 = *(const v8f*)&slab[sAB[s1] + vo];
            const v8f B1 = *(const v8f*)&slab[sAB[16 + s1] + vo];
            const float4 L1 = s_lut[s1];
            const v8f t1 = lut8(A1, B1, L1.x, L1.y, L1.z, L1.w);
            const float4 LN = s_lut[16 + j];
            v1[j] = lut8(t0, t1, LN.x, LN.y, LN.z, LN.w);
        }

        // ---- levels 2..4: widths 4,2,1 at node offsets 24,28,30 ----
        #pragma unroll
        for (int j = 0; j < 4; ++j) {
            const float4 L = s_lut[24 + j];
            v1[j] = lut8(v1[2 * j], v1[2 * j + 1], L.x, L.y, L.z, L.w);
        }
        #pragma unroll
        for (int j = 0; j < 2; ++j) {
            const float4 L = s_lut[28 + j];
            v1[j] = lut8(v1[2 * j], v1[2 * j + 1], L.x, L.y, L.z, L.w);
        }
        {
            const float4 L = s_lut[30];
            v1[0] = lut8(v1[0], v1[1], L.x, L.y, L.z, L.w);
        }

        // store 8 consecutive od (gq=3 overlaps gq=2 with identical values)
        const int oh = blockIdx.y * 2 + ohl;
        float* outp = out + (size_t)bk * 27000 + oh * 900 + ow * 30 + od0;
        *(v8f*)outp = v1[0];
    }
}

extern "C" void kernel_launch(void* const* d_in, const int* in_sizes, int n_in,
                              void* d_out, int out_size, void* d_ws, size_t ws_size,
                              hipStream_t stream) {
    const float* x  = (const float*)d_in[0];
    const int*   kc = (const int*)d_in[1];
    const float* w0 = (const float*)d_in[2];
    const float* w1 = (const float*)d_in[3];
    const float* w2 = (const float*)d_in[4];
    const float* w3 = (const float*)d_in[5];
    const float* w4 = (const float*)d_in[6];
    float* out = (float*)d_out;

    dim3 grid(B_ * K_, 15);  // (bk, oh-pair) = 1920 blocks
    logic_conv3d<<<grid, TPB, 0, stream>>>(x, kc, w0, w1, w2, w3, w4, out);
}

// Round 11
// 84.386 us; speedup vs baseline: 1.0643x; 1.0368x over previous
//
#include <hip/hip_runtime.h>

// LogicConv3d: B=4, C=3, H=W=D=32, K=32, S=16 leaves, tree depth 4 (31 LUT nodes).
// Out: (B, K, 30, 30, 30) = 3,456,000 fp32.
//
// R10: split gathers across BOTH memory pipes. Evidence: R5 (all-global) and
// R9 (all-LDS) both plateau at ~27.5us kernel — each saturates one pipe
// (L1/VMEM resp. the per-CU LDS unit) at 128 B/output while the other idles.
// -> A-leaves (16) from the LDS slab (ds_read2_b32 pairs),
//    B-leaves (16) from global x (L2-resident; od-octets never cross a 128B
//    d-row, so each v8f is two same-line dwordx4).
// Structure otherwise = R9: 8-od octets, 2 oh rows/block (slab 50.7 KB,
// 3 blocks/CU), levels 0+1 fused (64-VGPR accumulator cap), bases in SGPRs.

#define B_  4
#define C_  3
#define H_  32
#define W_  32
#define D_  32
#define K_  32
#define S_  16
#define WS  33      // padded d-row stride (dwords); %32==1 rotates banks per ow
#define TPB 256

typedef float v8f __attribute__((ext_vector_type(8), aligned(4)));

__device__ __forceinline__ v8f lut8(v8f a, v8f b, float l0, float d1, float d2, float d3) {
    // E = l0 + a*d2 + b*d1 + (a*b)*d3 == fma(b, fma(a,d3,d1), fma(a,d2,l0))
    const v8f t0 = a * d2 + l0;
    const v8f t1 = a * d3 + d1;
    return b * t1 + t0;
}

__global__ __launch_bounds__(TPB, 3) void logic_conv3d(
    const float* __restrict__ x,
    const int*   __restrict__ kc,
    const float* __restrict__ w0,
    const float* __restrict__ w1,
    const float* __restrict__ w2,
    const float* __restrict__ w3,
    const float* __restrict__ w4,
    float*       __restrict__ out)
{
    __shared__ float4 s_lut[31];                 // (l0, d1, d2, d3) per node
    __shared__ int    s_lb[16];                  // A-leaf base, slab coords
    __shared__ int    s_gb[16];                  // B-leaf base, global dword coords (oh-independent)
    __shared__ __align__(16) float slab[12 * 32 * WS];  // 12672 dwords = 50688 B

    const int bk  = blockIdx.x;      // b*K + k
    const int b   = bk >> 5;
    const int k   = bk & 31;
    const int tid = threadIdx.x;

    // ---- per-block setup: 31 softmax->LUT (delta form) + 32 leaf bases ----
    if (tid < 31) {
        const float* wp; int ln;
        if      (tid < 16) { wp = w0; ln = tid;      }
        else if (tid < 24) { wp = w1; ln = tid - 16; }
        else if (tid < 28) { wp = w2; ln = tid - 24; }
        else if (tid < 30) { wp = w3; ln = tid - 28; }
        else               { wp = w4; ln = 0;        }
        const float* wrow = wp + (ln * K_ + k) * 16;
        float lg[16];
        float m = -1e30f;
        #pragma unroll
        for (int g = 0; g < 16; ++g) { lg[g] = wrow[g]; m = fmaxf(m, lg[g]); }
        float z = 0.f;
        #pragma unroll
        for (int g = 0; g < 16; ++g) { lg[g] = __expf(lg[g] - m); z += lg[g]; }
        const float inv = 1.0f / z;
        float l0 = 0.f, l1 = 0.f, l2 = 0.f, l3 = 0.f;
        #pragma unroll
        for (int g = 0; g < 16; ++g) {
            float p = lg[g] * inv;           // GATES[g,t] = (g>>t)&1, t = 2*a+b
            if (g & 1) l0 += p;
            if (g & 2) l1 += p;
            if (g & 4) l2 += p;
            if (g & 8) l3 += p;
        }
        s_lut[tid] = make_float4(l0, l1 - l0, l2 - l0, (l3 - l2) - (l1 - l0));
    } else if (tid >= 32 && tid < 64) {
        const int idx  = tid - 32;           // tree*16 + s
        const int tree = idx >> 4;
        const int s    = idx & 15;
        const int off  = ((tree * K_ + k) * S_ + s) * 4;  // kc (2,K,S,4) = (h,w,d,c)
        const int h = kc[off + 0], w = kc[off + 1], d = kc[off + 2], c = kc[off + 3];
        if (tree == 0)
            s_lb[s] = ((c * 4 + h) * 32 + w) * WS + d;        // slab coords (4 h-rows)
        else
            s_gb[s] = ((c * H_ + h) * W_ + w) * D_ + d;       // global coords, oh folded later
    }

    // ---- stage slab: 12 planes (3c x 4h) of 32x32 dwords, coalesced float4 ----
    {
        const float* xb = x + (size_t)b * (C_ * H_ * W_ * D_) + (blockIdx.y * 2) * (W_ * D_);
        const int w  = tid >> 3;             // 0..31
        const int d4 = (tid & 7) << 2;       // 0,4,...,28
        #pragma unroll
        for (int it = 0; it < 12; ++it) {
            const int c  = it >> 2;          // 0..2
            const int dh = it & 3;           // 0..3
            const float4 val = *(const float4*)(xb + c * (H_ * W_ * D_) + dh * (W_ * D_) + tid * 4);
            *(float4*)&slab[((c * 4 + dh) * 32 + w) * WS + d4] = val;
        }
    }
    __syncthreads();

    // ---- bases: aligned b128 reads + readfirstlane -> SGPRs ----
    int sA[16], sB[16];
    #pragma unroll
    for (int i = 0; i < 4; ++i) {
        const int4 qa = *(const int4*)&s_lb[i * 4];
        sA[i * 4 + 0] = __builtin_amdgcn_readfirstlane(qa.x);
        sA[i * 4 + 1] = __builtin_amdgcn_readfirstlane(qa.y);
        sA[i * 4 + 2] = __builtin_amdgcn_readfirstlane(qa.z);
        sA[i * 4 + 3] = __builtin_amdgcn_readfirstlane(qa.w);
        const int4 qb = *(const int4*)&s_gb[i * 4];
        sB[i * 4 + 0] = __builtin_amdgcn_readfirstlane(qb.x);
        sB[i * 4 + 1] = __builtin_amdgcn_readfirstlane(qb.y);
        sB[i * 4 + 2] = __builtin_amdgcn_readfirstlane(qb.z);
        sB[i * 4 + 3] = __builtin_amdgcn_readfirstlane(qb.w);
    }

    // thread -> (oh_local, ow, octet of consecutive od)
    const int ohl = tid >> 7;                // 0,1
    const int r   = tid & 127;
    const int ow  = r >> 2;                  // 0..31 (>=30 inactive)
    const int gq  = r & 3;                   // 0..3
    const int od0 = (gq < 3) ? (gq << 3) : 22;  // 0,8,16,22; gq=3 overlaps gq=2 by 2

    if (ow < 30) {
        const int vo  = ohl * (32 * WS) + ow * WS + od0;            // slab offset (A)
        const int gvo = ohl * (W_ * D_) + ow * D_ + od0;            // global offset (B)
        const float* xg = x + (size_t)b * (C_ * H_ * W_ * D_) + (blockIdx.y * 2) * (W_ * D_);

        // ---- fused levels 0+1: leaf pair -> level-1 node ----
        v8f v1[8];
        #pragma unroll
        for (int j = 0; j < 8; ++j) {
            const int s0 = 2 * j, s1 = 2 * j + 1;
            const v8f A0 = *(const v8f*)&slab[sA[s0] + vo];
            const v8f B0 = *(const v8f*)(xg + sB[s0] + gvo);
            const float4 L0 = s_lut[s0];
            const v8f t0 = lut8(A0, B0, L0.x, L0.y, L0.z, L0.w);
            const v8f A1 = *(const v8f*)&slab[sA[s1] + vo];
            const v8f B1 = *(const v8f*)(xg + sB[s1] + gvo);
            const float4 L1 = s_lut[s1];
            const v8f t1 = lut8(A1, B1, L1.x, L1.y, L1.z, L1.w);
            const float4 LN = s_lut[16 + j];
            v1[j] = lut8(t0, t1, LN.x, LN.y, LN.z, LN.w);
        }

        // ---- levels 2..4: widths 4,2,1 at node offsets 24,28,30 ----
        #pragma unroll
        for (int j = 0; j < 4; ++j) {
            const float4 L = s_lut[24 + j];
            v1[j] = lut8(v1[2 * j], v1[2 * j + 1], L.x, L.y, L.z, L.w);
        }
        #pragma unroll
        for (int j = 0; j < 2; ++j) {
            const float4 L = s_lut[28 + j];
            v1[j] = lut8(v1[2 * j], v1[2 * j + 1], L.x, L.y, L.z, L.w);
        }
        {
            const float4 L = s_lut[30];
            v1[0] = lut8(v1[0], v1[1], L.x, L.y, L.z, L.w);
        }

        // store 8 consecutive od (gq=3 overlaps gq=2 with identical values)
        const int oh = blockIdx.y * 2 + ohl;
        float* outp = out + (size_t)bk * 27000 + oh * 900 + ow * 30 + od0;
        *(v8f*)outp = v1[0];
    }
}

extern "C" void kernel_launch(void* const* d_in, const int* in_sizes, int n_in,
                              void* d_out, int out_size, void* d_ws, size_t ws_size,
                              hipStream_t stream) {
    const float* x  = (const float*)d_in[0];
    const int*   kc = (const int*)d_in[1];
    const float* w0 = (const float*)d_in[2];
    const float* w1 = (const float*)d_in[3];
    const float* w2 = (const float*)d_in[4];
    const float* w3 = (const float*)d_in[5];
    const float* w4 = (const float*)d_in[6];
    float* out = (float*)d_out;

    dim3 grid(B_ * K_, 15);  // (bk, oh-pair) = 1920 blocks
    logic_conv3d<<<grid, TPB, 0, stream>>>(x, kc, w0, w1, w2, w3, w4, out);
}